// Round 7
// baseline (5796.388 us; speedup 1.0000x reference)
//
#include <hip/hip_runtime.h>
#include <math.h>

#define B_  64
#define T_  800
#define U_  64
#define V_  60
#define C_  512
#define K_  10
#define KX  576   // padded hx: [0..3]=x(3)+pad, [4..63]=w(60), [64..575]=h(512)
#define NWG 256
#define NTH 1024  // 16 waves: (kqA = w&7) x (colhalf = w>>3)
#define KQ  8     // k-split for gates GEMM
#define KSL 72    // KX / KQ
#define NB  4     // batches per group
#define GRPWG 16  // WGs per group; bid%8 == grp%8 -> same XCD under round-robin

typedef unsigned long long ull;

// ws: [0 .. 512KB)   hl[2][B][C] ull — XCD-L2 fast-path (plain store / sc0 load)
//     [512KB .. 1MB) hg[2][B][C] ull — MALL fallback   (sc1 store / sc1 load)
#define HL_N (2*B_*C_)

__device__ __forceinline__ float sigm(float v)  { return 1.f/(1.f+__expf(-v)); }
__device__ __forceinline__ float tanhx(float v) { return 1.f - 2.f/(__expf(2.f*v)+1.f); }

// 16B load, L1-bypass, served by the XCD-local L2
__device__ __forceinline__ ulonglong2 ld16_sc0(const ull* p) {
  ulonglong2 r;
  asm volatile("global_load_dwordx4 %0, %1, off sc0\n\ts_waitcnt vmcnt(0)"
               : "=v"(r) : "v"(p) : "memory");
  return r;
}
// 16B load, L1+L2 bypass (device-coherent, MALL)
__device__ __forceinline__ ulonglong2 ld16_sc01(const ull* p) {
  ulonglong2 r;
  asm volatile("global_load_dwordx4 %0, %1, off sc0 sc1\n\ts_waitcnt vmcnt(0)"
               : "=v"(r) : "v"(p) : "memory");
  return r;
}

__global__ __launch_bounds__(NTH)
void lstm_attn_persistent(
    const float* __restrict__ x,         // [B,T,3]
    const float* __restrict__ onehots,   // [B,U,V]
    const float* __restrict__ text_lens, // [B,1]
    const float* __restrict__ w_old,     // [B,V]
    const float* __restrict__ kappa_old, // [B,K]
    const float* __restrict__ prev_h,    // [B,C]
    const float* __restrict__ prev_c,    // [B,C]
    const float* __restrict__ W_ih,      // [4C, 63]
    const float* __restrict__ W_hh,      // [4C, C]
    const float* __restrict__ b_ih,      // [4C]
    const float* __restrict__ b_hh,      // [4C]
    const float* __restrict__ win_W,     // [30, C]
    const float* __restrict__ win_b,     // [30]
    ull* __restrict__ hl,
    float* __restrict__ out)
{
  // out layout (flat, return order)
  const long OUT_WS  = 0;
  const long OUT_HS  = (long)B_*T_*V_;
  const long OUT_H   = OUT_HS + (long)B_*T_*C_;
  const long OUT_C   = OUT_H  + (long)B_*C_;
  const long OUT_W   = OUT_C  + (long)B_*C_;
  const long OUT_KAP = OUT_W  + (long)B_*V_;
  const long OUT_PHI = OUT_KAP+ (long)B_*K_;

  ull* hg = hl + HL_N;

  const int tid  = threadIdx.x;
  const int wav  = tid >> 6;        // 0..15
  const int kqA  = wav & 7;         // gates k-slice
  const int sA   = wav >> 3;        // gates col-half (64 cols each)
  const int lane = tid & 63;
  const int bid  = blockIdx.x;
  const int grp  = bid & 15;        // group id (4 batches); bid%8 fixed per group
  const int gblk = bid >> 4;        // 0..15: 128-gate-col block
  const int b0   = grp * NB;

  __shared__ __align__(16) float hx[NB][KX];          // per-b extended input vector
  __shared__ __align__(16) float part[KQ][NB][2][68]; // gates: [kqA][bb][sA][lane]; win: [wav>>1][bb][wav&1][lane]
  __shared__ float p_lds[NB][32];
  __shared__ float kap_lds[NB][12];
  __shared__ float scale_lds[NB];
  __shared__ int   ids_lds[NB][64];

  // ---- persistent registers ----
  // permuted gate col gp = ch*4 + gate; this thread owns ONE col
  float Wreg[KSL];
  float bias1;
  {
    int gp   = gblk*128 + sA*64 + lane;
    int gate = gp & 3;
    int ch   = gp >> 2;
    int row  = gate*C_ + ch;
    #pragma unroll
    for (int i = 0; i < KSL; ++i) {
      int k = kqA*KSL + i;
      float v;
      if      (k < 3)  v = W_ih[row*63 + k];
      else if (k == 3) v = 0.f;
      else if (k < 64) v = W_ih[row*63 + (k-1)];
      else             v = W_hh[row*C_ + (k-64)];
      Wreg[i] = v;
    }
    bias1 = b_ih[row] + b_hh[row];
  }

  // window projection: 16-way ch-split; lane -> (wj = lane%30, wh = lane/30)
  const int wj = lane % 30;
  const int wh = (lane < 60) ? (lane / 30) : 0;
  float winreg[16];
  #pragma unroll
  for (int i = 0; i < 16; ++i)
    winreg[i] = win_W[wj*C_ + wav*32 + wh*16 + i];

  // LSTM cell state: tid<128 owns (bb = tid>>5, ch = gblk*32 + (tid&31))
  const int ub    = tid >> 5;       // 0..3 when tid<128
  const int chloc = tid & 31;
  const int mych  = gblk*32 + chloc;
  float c_reg = 0.f;
  if (tid < 128) c_reg = prev_c[(long)(b0 + ub)*C_ + mych];

  float winb_r = (tid < 120) ? win_b[tid % 30] : 0.f;

  // ---- preamble staging ----
  for (int i = tid; i < NB*KX; i += NTH) {
    int bb = i / KX, k = i % KX;
    int b = b0 + bb;
    float v;
    if      (k < 3)  v = x[((long)b*T_ + 0)*3 + k];
    else if (k < 4)  v = 0.f;
    else if (k < 64) v = w_old[b*V_ + (k-4)];
    else             v = prev_h[(long)b*C_ + (k-64)];
    hx[bb][k] = v;
  }
  for (int i = tid; i < NB*K_; i += NTH)
    kap_lds[i/K_][i%K_] = kappa_old[(b0 + i/K_)*K_ + i%K_];
  if (tid < NB) scale_lds[tid] = (float)U_ / text_lens[b0 + tid];
  for (int i = tid; i < NB*U_; i += NTH) {          // one-hot -> char id
    int bb = i / U_, u = i % U_;
    const float* oh = onehots + ((long)(b0+bb)*U_ + u)*V_;
    int best = 0; float bv = oh[0];
    for (int vv = 1; vv < V_; ++vv) { float q = oh[vv]; if (q > bv) { bv = q; best = vv; } }
    ids_lds[bb][u] = best;
  }
  __syncthreads();

  int fb_after = 24;   // local-L2 poll budget; collapses to 0 if fallback ever used

  for (int t = 0; t < T_; ++t) {
    // ---- A: gates GEMM (k-split x col-split across 16 waves; 1 col/lane) ----
    float acc[NB];
    #pragma unroll
    for (int bb = 0; bb < NB; ++bb) acc[bb] = (kqA == 0) ? bias1 : 0.f;
    #pragma unroll
    for (int bb = 0; bb < NB; ++bb) {
      const float* hxb = &hx[bb][kqA*KSL];
      float a = acc[bb];
      #pragma unroll
      for (int i4 = 0; i4 < KSL/4; ++i4) {
        float4 h4 = *(const float4*)(hxb + i4*4);
        a = fmaf(Wreg[i4*4+0], h4.x, a);
        a = fmaf(Wreg[i4*4+1], h4.y, a);
        a = fmaf(Wreg[i4*4+2], h4.z, a);
        a = fmaf(Wreg[i4*4+3], h4.w, a);
      }
      acc[bb] = a;
    }
    #pragma unroll
    for (int bb = 0; bb < NB; ++bb)
      part[kqA][bb][sA][lane] = acc[bb];
    __syncthreads();   // B

    // ---- C: cell update + dual h publish | zero w-slots | stage x(t+1) ----
    if (tid < 128) {
      const int sr = chloc >> 4, c4 = (chloc & 15) * 4;
      float4 s = make_float4(0.f, 0.f, 0.f, 0.f);
      #pragma unroll
      for (int q = 0; q < KQ; ++q) {
        float4 v = *(const float4*)&part[q][ub][sr][c4];
        s.x += v.x; s.y += v.y; s.z += v.z; s.w += v.w;
      }
      float ig = sigm(s.x), fg = sigm(s.y), gg = tanhx(s.z), og = sigm(s.w);
      float c = fg*c_reg + ig*gg;
      c_reg = c;
      float h = og * tanhx(c);
      int b = b0 + ub;
      ull pk = ((ull)(unsigned)(t+1) << 32) | (ull)__float_as_uint(h);
      long hidx = (long)(t&1)*B_*C_ + (long)b*C_ + mych;
      hl[hidx] = pk;                                   // XCD-local L2 copy
      __hip_atomic_store(&hg[hidx], pk,                // MALL copy (fallback)
                         __ATOMIC_RELAXED, __HIP_MEMORY_SCOPE_AGENT);
      out[OUT_HS + ((long)b*T_ + t)*C_ + mych] = h;
      if (t == T_-1) {
        out[OUT_H + (long)b*C_ + mych] = h;
        out[OUT_C + (long)b*C_ + mych] = c;
      }
    } else if (tid < 368) {
      int s0 = tid - 128;                 // zero 240 w-slots
      hx[s0/60][4 + s0%60] = 0.f;
    } else if (tid < 384) {
      int i = tid - 368, bb = i >> 2, k = i & 3;
      int tn = t + 1;
      hx[bb][k] = (k < 3 && tn < T_) ? x[((long)(b0+bb)*T_ + tn)*3 + k] : 0.f;
    }
    // no sync: G gated by data-dependency poll; writes disjoint LDS

    // ---- G: poll-gather h (2 pairs/thread) — local L2 first, MALL fallback ----
    {
      const long base = (long)(t&1)*B_*C_ + (long)b0*C_ + tid*2;
      const ull* pl = hl + base;
      const ull* pg = hg + base;
      const int want = t + 1;
      ulonglong2 r;
      int it = 0;
      while (true) {
        r = (it < fb_after) ? ld16_sc0(pl) : ld16_sc01(pg);
        if ((int)(r.x >> 32) >= want && (int)(r.y >> 32) >= want) {
          if (it >= fb_after) fb_after = 0;   // mapping not XCD-local: stay on MALL
          break;
        }
        ++it;
      }
      int off = tid * 2, bb = off >> 9, k = off & 511;
      *(float2*)&hx[bb][64 + k] =
          make_float2(__uint_as_float((unsigned)r.x), __uint_as_float((unsigned)r.y));
    }
    __syncthreads();   // H

    // ---- I: window projection partials (16-way ch-split, lanes 0..59) ----
    #pragma unroll
    for (int bb = 0; bb < NB; ++bb) {
      const float* hb = &hx[bb][64 + wav*32 + wh*16];
      float a = 0.f;
      #pragma unroll
      for (int i4 = 0; i4 < 4; ++i4) {
        float4 h4 = *(const float4*)(hb + i4*4);
        a = fmaf(winreg[i4*4+0], h4.x, a);
        a = fmaf(winreg[i4*4+1], h4.y, a);
        a = fmaf(winreg[i4*4+2], h4.z, a);
        a = fmaf(winreg[i4*4+3], h4.w, a);
      }
      if (lane < 60) part[wav>>1][bb][wav&1][lane] = a;
    }
    __syncthreads();   // J

    // ---- K: reduce 32 partials -> p = exp(.+winb); update kappa ----
    if (tid < 120) {
      int bb = tid / 30, j = tid % 30;
      float s = 0.f;
      #pragma unroll
      for (int q = 0; q < KQ; ++q) {
        s += part[q][bb][0][j] + part[q][bb][0][30+j];
        s += part[q][bb][1][j] + part[q][bb][1][30+j];
      }
      float p = __expf(s + winb_r);
      p_lds[bb][j] = p;
      if (j >= 20) {
        float nk = kap_lds[bb][j-20] + p;
        kap_lds[bb][j-20] = nk;
        if (t == T_-1 && gblk == 0) out[OUT_KAP + (b0+bb)*K_ + (j-20)] = nk;
      }
    }
    __syncthreads();   // L

    // ---- M (waves 0-3): fused phi + w-scatter (wave = batch; u = lane) ----
    if (wav < NB) {
      int bb = wav, u = lane;
      float s = 0.f;
      float uf = (float)u;
      #pragma unroll
      for (int k = 0; k < K_; ++k) {
        float d = kap_lds[bb][k] - uf;
        s += p_lds[bb][k] * __expf(-p_lds[bb][10+k]*d*d);
      }
      float phiv = s * scale_lds[bb];
      atomicAdd(&hx[bb][4 + ids_lds[bb][u]], phiv);   // ds_add_f32, in-wave order
      if (t == T_-1 && gblk == 0) out[OUT_PHI + (b0+bb)*65 + u] = phiv;
    }
    if (t == T_-1 && gblk == 0 && tid < NB) {         // u = 64 tail of phi output
      int b2 = tid;
      float s2 = 0.f;
      #pragma unroll
      for (int k = 0; k < K_; ++k) {
        float d = kap_lds[b2][k] - 64.f;
        s2 += p_lds[b2][k] * __expf(-p_lds[b2][10+k]*d*d);
      }
      out[OUT_PHI + (b0+b2)*65 + 64] = s2 * scale_lds[b2];
    }
    __syncthreads();   // N: scatter complete -> w readable

    // ---- O: rotated ws-store (one WG of the group per step) ----
    if (gblk == (t & 15) && tid < 240) {
      int bb = tid / 60, v = tid % 60;
      float wv = hx[bb][4+v];
      out[OUT_WS + ((long)(b0+bb)*T_ + t)*V_ + v] = wv;
      if (t == T_-1) out[OUT_W + (b0+bb)*V_ + v] = wv;
    }
    // no sync: O and next-A only read hx; first hx write is next-C (post-B sync)
  }
}

extern "C" void kernel_launch(void* const* d_in, const int* in_sizes, int n_in,
                              void* d_out, int out_size, void* d_ws, size_t ws_size,
                              hipStream_t stream) {
  const float* x         = (const float*)d_in[0];
  const float* onehots   = (const float*)d_in[1];
  const float* text_lens = (const float*)d_in[2];
  const float* w_old     = (const float*)d_in[3];
  const float* kappa_old = (const float*)d_in[4];
  const float* prev_h    = (const float*)d_in[5];
  const float* prev_c    = (const float*)d_in[6];
  const float* W_ih      = (const float*)d_in[7];
  const float* W_hh      = (const float*)d_in[8];
  const float* b_ih      = (const float*)d_in[9];
  const float* b_hh      = (const float*)d_in[10];
  const float* win_W     = (const float*)d_in[11];
  const float* win_b     = (const float*)d_in[12];
  ull*   hl  = (ull*)d_ws;
  float* out = (float*)d_out;

  // zero both tagged h regions (stale tags from prior replay must read < 1)
  hipMemsetAsync(d_ws, 0, 2ull*HL_N*sizeof(ull), stream);

  lstm_attn_persistent<<<NWG, NTH, 0, stream>>>(
      x, onehots, text_lens, w_old, kappa_old, prev_h, prev_c,
      W_ih, W_hh, b_ih, b_hh, win_W, win_b, hl, out);
}